// Round 12
// baseline (243.047 us; speedup 1.0000x reference)
//
#include <hip/hip_runtime.h>
#include <math.h>

#define Bq 2
#define Lq 2048
#define Eq 1024
#define Hq 16
#define Dq 64

typedef __attribute__((ext_vector_type(8))) short bf16x8;
typedef __attribute__((ext_vector_type(4))) short bf16x4;
typedef __attribute__((ext_vector_type(4))) float f32x4;
typedef _Float16 f16;
typedef __attribute__((ext_vector_type(4))) _Float16 f16x4;

__device__ __forceinline__ short f2bf(float f) {
    union { float f; unsigned u; } x; x.f = f;
    unsigned r = x.u + 0x7FFFu + ((x.u >> 16) & 1u);
    return (short)(r >> 16);
}
__device__ __forceinline__ float bf2f(short s) {
    union { unsigned u; float f; } x;
    x.u = ((unsigned)(unsigned short)s) << 16;
    return x.f;
}
__device__ __forceinline__ short f2h_bits(float v) {
    union { f16 h; short s; } u; u.h = (f16)v; return u.s;
}

// Cast Q,K,V (4096x1024 f32) and Wq,Wk,Wv (1024x1024 f32) to bf16, laid out
// consecutively in `out`: [Xq | Xk | Xv | Wqb | Wkb | Wvb]. Tail blocks zero `os`.
__global__ __launch_bounds__(256) void cast_all(const float* __restrict__ Q,
                                                const float* __restrict__ K,
                                                const float* __restrict__ V,
                                                const float* __restrict__ Wq,
                                                const float* __restrict__ Wk,
                                                const float* __restrict__ Wv,
                                                short* __restrict__ out,
                                                float* __restrict__ os) {
    const size_t NX = (size_t)4096 * 1024 / 4;  // float4 count per X
    const size_t NW = (size_t)1024 * 1024 / 4;  // float4 count per W
    const size_t TOT = 3 * NX + 3 * NW;
    size_t id = (size_t)blockIdx.x * 256 + threadIdx.x;
    if (id >= TOT) {
        size_t z = id - TOT;
        if (z < (size_t)(Bq * Eq / 4)) {
            float4 zv = {0.f, 0.f, 0.f, 0.f};
            ((float4*)os)[z] = zv;
        }
        return;
    }
    const float* src; size_t off;
    if (id < NX)              { src = Q;  off = id; }
    else if (id < 2 * NX)     { src = K;  off = id - NX; }
    else if (id < 3 * NX)     { src = V;  off = id - 2 * NX; }
    else if (id < 3 * NX + NW)     { src = Wq; off = id - 3 * NX; }
    else if (id < 3 * NX + 2 * NW) { src = Wk; off = id - 3 * NX - NW; }
    else                           { src = Wv; off = id - 3 * NX - 2 * NW; }
    float4 v = ((const float4*)src)[off];
    bf16x4 s;
    s[0] = f2bf(v.x); s[1] = f2bf(v.y); s[2] = f2bf(v.z); s[3] = f2bf(v.w);
    ((bf16x4*)out)[id] = s;
}

// All three projections. Block tile 128x128, BK=32, wave tile 64x64.
// Padded-LDS staging (stride 40) with register double-buffer.
// pidx 0/1 outputs bf16 (+ sumsq); pidx 2 outputs vT in F16 (PV runs in f16).
__global__ __launch_bounds__(256) void proj3_kernel(const short* __restrict__ castb,
                                                    short* __restrict__ qb,
                                                    short* __restrict__ kb,
                                                    short* __restrict__ vT,
                                                    float* __restrict__ q2,
                                                    float* __restrict__ k2) {
    const int wave = threadIdx.x >> 6;
    const int lane = threadIdx.x & 63;
    const int l15 = lane & 15, quad = lane >> 4;
    const int pidx = blockIdx.y >> 3;
    const short* Xb = castb + (size_t)pidx * 4096 * 1024;
    const short* Wb = castb + (size_t)3 * 4096 * 1024 + (size_t)pidx * 1024 * 1024;
    short* outb = (pidx == 0) ? qb : (pidx == 1) ? kb : vT;
    float* x2 = (pidx == 0) ? q2 : (pidx == 1) ? k2 : nullptr;
    const int transposed = (pidx == 2);
    const int m0 = blockIdx.x * 128;
    const int n0 = (blockIdx.y & 7) * 128;
    const int wm = wave & 1, wn = wave >> 1;

    __shared__ __align__(16) short lds_a[128 * 40];
    __shared__ __align__(16) short lds_b[128 * 40];

    const int r0 = threadIdx.x >> 2;            // rows 0..63
    const int r1 = 64 + r0;                     // rows 64..127
    const int cc = (threadIdx.x & 3) * 8;       // col chunk (shorts)
    const short* gA0 = Xb + (size_t)(m0 + r0) * Eq + cc;
    const short* gA1 = Xb + (size_t)(m0 + r1) * Eq + cc;
    const short* gB0 = Wb + (size_t)(n0 + r0) * Eq + cc;
    const short* gB1 = Wb + (size_t)(n0 + r1) * Eq + cc;
    short* la0 = lds_a + r0 * 40 + cc;
    short* la1 = lds_a + r1 * 40 + cc;
    short* lb0 = lds_b + r0 * 40 + cc;
    short* lb1 = lds_b + r1 * 40 + cc;

    f32x4 acc[4][4] = {};
    bf16x8 pa0 = *(const bf16x8*)gA0;
    bf16x8 pa1 = *(const bf16x8*)gA1;
    bf16x8 pb0 = *(const bf16x8*)gB0;
    bf16x8 pb1 = *(const bf16x8*)gB1;

#pragma unroll 1
    for (int e0 = 0; e0 < Eq; e0 += 32) {
        __syncthreads();
        *(bf16x8*)la0 = pa0; *(bf16x8*)la1 = pa1;
        *(bf16x8*)lb0 = pb0; *(bf16x8*)lb1 = pb1;
        if (e0 + 32 < Eq) {
            pa0 = *(const bf16x8*)(gA0 + e0 + 32);
            pa1 = *(const bf16x8*)(gA1 + e0 + 32);
            pb0 = *(const bf16x8*)(gB0 + e0 + 32);
            pb1 = *(const bf16x8*)(gB1 + e0 + 32);
        }
        __syncthreads();

        bf16x8 af[4], bfr[4];
#pragma unroll
        for (int i = 0; i < 4; ++i)
            af[i] = *(const bf16x8*)(lds_a + (wm * 64 + i * 16 + l15) * 40 + quad * 8);
#pragma unroll
        for (int j = 0; j < 4; ++j)
            bfr[j] = *(const bf16x8*)(lds_b + (wn * 64 + j * 16 + l15) * 40 + quad * 8);
#pragma unroll
        for (int i = 0; i < 4; ++i)
#pragma unroll
            for (int j = 0; j < 4; ++j)
                acc[i][j] = __builtin_amdgcn_mfma_f32_16x16x32_bf16(af[i], bfr[j], acc[i][j], 0, 0, 0);
    }

    const int mw = m0 + wm * 64;
    const int nw = n0 + wn * 64;
    const int h = nw >> 6;
#pragma unroll
    for (int i = 0; i < 4; ++i) {
        float ss[4] = {0.f, 0.f, 0.f, 0.f};
#pragma unroll
        for (int r = 0; r < 4; ++r) {
            int tok = mw + i * 16 + quad * 4 + r;
            int b = tok >> 11, l = tok & 2047;
#pragma unroll
            for (int j = 0; j < 4; ++j) {
                int d = (nw + j * 16 + l15) & 63;
                float av = acc[i][j][r];
                short sb;
                size_t idx;
                if (transposed) {
                    sb = f2h_bits(av);   // V path: store f16 for the f16 PV MFMA
                    idx = ((size_t)(b * Hq + h) * Dq + d) * Lq + l;
                } else {
                    sb = f2bf(av);
                    float sv = bf2f(sb);
                    ss[r] += sv * sv;
                    idx = ((size_t)(b * Hq + h) * Lq + l) * Dq + d;
                }
                outb[idx] = sb;
            }
        }
        if (x2 != nullptr) {
#pragma unroll
            for (int r = 0; r < 4; ++r) {
#pragma unroll
                for (int off = 1; off < 16; off <<= 1) ss[r] += __shfl_xor(ss[r], off);
            }
            if (l15 == 0) {
#pragma unroll
                for (int r = 0; r < 4; ++r) {
                    int tok = mw + i * 16 + quad * 4 + r;
                    int b = tok >> 11, l = tok & 2047;
                    x2[(size_t)(b * Hq + h) * Lq + l] = ss[r];
                }
            }
        }
    }
}

// Flash attention, scores = -||q-k||, fixed softmax max = 0. NO P transpose:
// S^T = K.Q^T (swapped MFMA operands) leaves each lane holding P[q=l15][key=quad*4+r]
// — exactly the A-fragment layout of mfma_f32_16x16x16f16 — so P goes straight
// from registers into the PV MFMA (V stored as f16 by proj3). K/V staged into
// padded LDS with register prefetch (r11 pattern). Grid (32, B*H), 256 thr.
__global__ __launch_bounds__(256) void flash_kernel(const short* __restrict__ qb,
                                                    const short* __restrict__ kb,
                                                    const short* __restrict__ vT,
                                                    const float* __restrict__ q2,
                                                    const float* __restrict__ k2,
                                                    float* __restrict__ osum) {
    const int wave = threadIdx.x >> 6;
    const int lane = threadIdx.x & 63;
    const int l15 = lane & 15, quad = lane >> 4;
    const int bh = blockIdx.y;
    const int q0 = blockIdx.x * 64 + wave * 16;
    const short* qbh = qb + (size_t)bh * Lq * Dq;
    const short* kbh = kb + (size_t)bh * Lq * Dq;
    const short* vbh = vT + (size_t)bh * Dq * Lq;
    const float* q2h = q2 + (size_t)bh * Lq;
    const float* k2h = k2 + (size_t)bh * Lq;

    __shared__ __align__(16) short lds_k[64 * 72];
    __shared__ __align__(16) short lds_v[64 * 72];

    // Q fragment (B-operand of S^T): lane l15 = q-row, cols quad*8..+7
    const short* qp = qbh + (size_t)(q0 + l15) * Dq + quad * 8;
    bf16x8 qf0 = *(const bf16x8*)qp;
    bf16x8 qf1 = *(const bf16x8*)(qp + 32);
    const float q2l = q2h[q0 + l15];

    // staging geometry: thread t covers 16B chunks t and t+256 of each 8KB tile
    const int row0 = threadIdx.x >> 3;
    const int row1 = 32 + row0;
    const int sc = (threadIdx.x & 7) * 8;
    short* lk0 = lds_k + row0 * 72 + sc;
    short* lk1 = lds_k + row1 * 72 + sc;
    short* lv0 = lds_v + row0 * 72 + sc;
    short* lv1 = lds_v + row1 * 72 + sc;

    f32x4 o[4] = {};
    float lsum = 0.f;

    // prologue: prefetch tile 0
    bf16x8 kp0 = *(const bf16x8*)(kbh + (size_t)row0 * Dq + sc);
    bf16x8 kp1 = *(const bf16x8*)(kbh + (size_t)row1 * Dq + sc);
    bf16x8 vp0 = *(const bf16x8*)(vbh + (size_t)row0 * Lq + sc);
    bf16x8 vp1 = *(const bf16x8*)(vbh + (size_t)row1 * Lq + sc);

#pragma unroll 1
    for (int k0 = 0; k0 < Lq; k0 += 64) {
        __syncthreads();
        *(bf16x8*)lk0 = kp0; *(bf16x8*)lk1 = kp1;
        *(bf16x8*)lv0 = vp0; *(bf16x8*)lv1 = vp1;
        if (k0 + 64 < Lq) {
            const short* ks = kbh + (size_t)(k0 + 64) * Dq;
            kp0 = *(const bf16x8*)(ks + (size_t)row0 * Dq + sc);
            kp1 = *(const bf16x8*)(ks + (size_t)row1 * Dq + sc);
            vp0 = *(const bf16x8*)(vbh + (size_t)row0 * Lq + k0 + 64 + sc);
            vp1 = *(const bf16x8*)(vbh + (size_t)row1 * Lq + k0 + 64 + sc);
        }
        __syncthreads();

#pragma unroll
        for (int kt = 0; kt < 4; ++kt) {
            // K fragment (A-operand of S^T): lane l15 = key, cols quad*8..+7
            bf16x8 kf0 = *(const bf16x8*)(lds_k + (kt * 16 + l15) * 72 + quad * 8);
            bf16x8 kf1 = *(const bf16x8*)(lds_k + (kt * 16 + l15) * 72 + 32 + quad * 8);
            f32x4 st = {0.f, 0.f, 0.f, 0.f};
            st = __builtin_amdgcn_mfma_f32_16x16x32_bf16(kf0, qf0, st, 0, 0, 0);
            st = __builtin_amdgcn_mfma_f32_16x16x32_bf16(kf1, qf1, st, 0, 0, 0);
            // lane holds S[q=l15][key = k0+kt*16+quad*4+r]
            float4 k2v = *(const float4*)(k2h + k0 + kt * 16 + quad * 4);
            f16x4 pa;
#pragma unroll
            for (int r = 0; r < 4; ++r) {
                float d2 = fmaxf(fmaf(st[r], -2.f, q2l + ((const float*)&k2v)[r]), 0.f);
                float pv = __expf(-__builtin_amdgcn_sqrtf(d2));
                lsum += pv;
                pa[r] = (f16)pv;
            }
            // PV: A = pa (P fragment, in-register), B = vT fragment (f16)
#pragma unroll
            for (int f = 0; f < 4; ++f) {
                f16x4 vf = *(const f16x4*)(lds_v + (f * 16 + l15) * 72 + kt * 16 + quad * 4);
                o[f] = __builtin_amdgcn_mfma_f32_16x16x16f16(pa, vf, o[f], 0, 0, 0);
            }
        }
    }

    // lsum: lane already sums its keys for q-row l15; reduce over the 4 quads
    lsum += __shfl_xor(lsum, 16);
    lsum += __shfl_xor(lsum, 32);
    // fetch lsum for q-row quad*4+r (held by lane quad*4+r)
    float lq[4];
#pragma unroll
    for (int r = 0; r < 4; ++r) lq[r] = __shfl(lsum, quad * 4 + r);
    // normalize rows (O: row=quad*4+r=q-row, col=l15=d), reduce over 16 q-rows
#pragma unroll
    for (int f = 0; f < 4; ++f) {
        float cs = o[f][0] / lq[0] + o[f][1] / lq[1] +
                   o[f][2] / lq[2] + o[f][3] / lq[3];
        cs += __shfl_xor(cs, 16);
        cs += __shfl_xor(cs, 32);
        if (quad == 0) atomicAdd(&osum[(size_t)bh * Dq + f * 16 + l15], cs);
    }
}

// out[b,j] = sum_e osum[b,e] * Wo[j,e]; one wave per output element
__global__ __launch_bounds__(256) void outproj_kernel(const float* __restrict__ osum,
                                                      const float* __restrict__ Wo,
                                                      float* __restrict__ out) {
    int idx = blockIdx.x * 4 + (threadIdx.x >> 6);
    int lane = threadIdx.x & 63;
    int b = idx >> 10, j = idx & 1023;
    const float* o = osum + (size_t)b * Eq;
    const float* w = Wo + (size_t)j * Eq;
    float4 s4 = {0.f, 0.f, 0.f, 0.f};
    for (int e = lane * 4; e < Eq; e += 256) {
        float4 ov = *(const float4*)(o + e);
        float4 wv = *(const float4*)(w + e);
        s4.x += ov.x * wv.x; s4.y += ov.y * wv.y;
        s4.z += ov.z * wv.z; s4.w += ov.w * wv.w;
    }
    float s = s4.x + s4.y + s4.z + s4.w;
#pragma unroll
    for (int off = 1; off < 64; off <<= 1) s += __shfl_xor(s, off);
    if (lane == 0) out[idx] = s;
}

extern "C" void kernel_launch(void* const* d_in, const int* in_sizes, int n_in,
                              void* d_out, int out_size, void* d_ws, size_t ws_size,
                              hipStream_t stream) {
    const float* Q  = (const float*)d_in[0];
    const float* K  = (const float*)d_in[1];
    const float* V  = (const float*)d_in[2];
    const float* Wq = (const float*)d_in[3];
    const float* Wk = (const float*)d_in[4];
    const float* Wv = (const float*)d_in[5];
    const float* Wo = (const float*)d_in[6];
    float* out = (float*)d_out;

    char* ws = (char*)d_ws;
    // [0,8M) qb | [8M,16M) kb | [16M,24M) vT | q2 | k2 | osum | [25M,55M) castb
    short* qb = (short*)ws;
    short* kb = (short*)(ws + (size_t)(8 << 20));
    short* vT = (short*)(ws + (size_t)(16 << 20));
    float* q2 = (float*)(ws + (size_t)(24 << 20));
    float* k2 = (float*)(ws + (size_t)(24 << 20) + (256 << 10));
    float* os = (float*)(ws + (size_t)(24 << 20) + (512 << 10));
    short* castb = (short*)(ws + (size_t)(25 << 20));

    cast_all<<<15362, 256, 0, stream>>>(Q, K, V, Wq, Wk, Wv, castb, os);
    proj3_kernel<<<dim3(32, 24), 256, 0, stream>>>(castb, qb, kb, vT, q2, k2);
    flash_kernel<<<dim3(32, 32), 256, 0, stream>>>(qb, kb, vT, q2, k2, os);
    outproj_kernel<<<512, 256, 0, stream>>>(os, Wo, out);
}

// Round 13
// 227.112 us; speedup vs baseline: 1.0702x; 1.0702x over previous
//
#include <hip/hip_runtime.h>
#include <math.h>

#define Bq 2
#define Lq 2048
#define Eq 1024
#define Hq 16
#define Dq 64

typedef __attribute__((ext_vector_type(8))) short bf16x8;
typedef __attribute__((ext_vector_type(4))) short bf16x4;
typedef __attribute__((ext_vector_type(4))) float f32x4;

__device__ __forceinline__ short f2bf(float f) {
    union { float f; unsigned u; } x; x.f = f;
    unsigned r = x.u + 0x7FFFu + ((x.u >> 16) & 1u);
    return (short)(r >> 16);
}
__device__ __forceinline__ short f2bf_fast(float f) {  // round-half-up: 2 VALU ops
    union { float f; unsigned u; } x; x.f = f;
    return (short)((x.u + 0x8000u) >> 16);
}
__device__ __forceinline__ float bf2f(short s) {
    union { unsigned u; float f; } x;
    x.u = ((unsigned)(unsigned short)s) << 16;
    return x.f;
}

// Cast Q,K,V (4096x1024 f32) and Wq,Wk,Wv (1024x1024 f32) to bf16, laid out
// consecutively in `out`: [Xq | Xk | Xv | Wqb | Wkb | Wvb]. Tail blocks zero `os`.
__global__ __launch_bounds__(256) void cast_all(const float* __restrict__ Q,
                                                const float* __restrict__ K,
                                                const float* __restrict__ V,
                                                const float* __restrict__ Wq,
                                                const float* __restrict__ Wk,
                                                const float* __restrict__ Wv,
                                                short* __restrict__ out,
                                                float* __restrict__ os) {
    const size_t NX = (size_t)4096 * 1024 / 4;  // float4 count per X
    const size_t NW = (size_t)1024 * 1024 / 4;  // float4 count per W
    const size_t TOT = 3 * NX + 3 * NW;
    size_t id = (size_t)blockIdx.x * 256 + threadIdx.x;
    if (id >= TOT) {
        size_t z = id - TOT;
        if (z < (size_t)(Bq * Eq / 4)) {
            float4 zv = {0.f, 0.f, 0.f, 0.f};
            ((float4*)os)[z] = zv;
        }
        return;
    }
    const float* src; size_t off;
    if (id < NX)              { src = Q;  off = id; }
    else if (id < 2 * NX)     { src = K;  off = id - NX; }
    else if (id < 3 * NX)     { src = V;  off = id - 2 * NX; }
    else if (id < 3 * NX + NW)     { src = Wq; off = id - 3 * NX; }
    else if (id < 3 * NX + 2 * NW) { src = Wk; off = id - 3 * NX - NW; }
    else                           { src = Wv; off = id - 3 * NX - 2 * NW; }
    float4 v = ((const float4*)src)[off];
    bf16x4 s;
    s[0] = f2bf(v.x); s[1] = f2bf(v.y); s[2] = f2bf(v.z); s[3] = f2bf(v.w);
    ((bf16x4*)out)[id] = s;
}

// All three projections. Block tile 128x128, BK=32, wave tile 64x64.
// Padded-LDS staging (stride 40) with register double-buffer. (r11-exact)
__global__ __launch_bounds__(256) void proj3_kernel(const short* __restrict__ castb,
                                                    short* __restrict__ qb,
                                                    short* __restrict__ kb,
                                                    short* __restrict__ vT,
                                                    float* __restrict__ q2,
                                                    float* __restrict__ k2) {
    const int wave = threadIdx.x >> 6;
    const int lane = threadIdx.x & 63;
    const int l15 = lane & 15, quad = lane >> 4;
    const int pidx = blockIdx.y >> 3;
    const short* Xb = castb + (size_t)pidx * 4096 * 1024;
    const short* Wb = castb + (size_t)3 * 4096 * 1024 + (size_t)pidx * 1024 * 1024;
    short* outb = (pidx == 0) ? qb : (pidx == 1) ? kb : vT;
    float* x2 = (pidx == 0) ? q2 : (pidx == 1) ? k2 : nullptr;
    const int transposed = (pidx == 2);
    const int m0 = blockIdx.x * 128;
    const int n0 = (blockIdx.y & 7) * 128;
    const int wm = wave & 1, wn = wave >> 1;

    __shared__ __align__(16) short lds_a[128 * 40];
    __shared__ __align__(16) short lds_b[128 * 40];

    const int r0 = threadIdx.x >> 2;            // rows 0..63
    const int r1 = 64 + r0;                     // rows 64..127
    const int cc = (threadIdx.x & 3) * 8;       // col chunk (shorts)
    const short* gA0 = Xb + (size_t)(m0 + r0) * Eq + cc;
    const short* gA1 = Xb + (size_t)(m0 + r1) * Eq + cc;
    const short* gB0 = Wb + (size_t)(n0 + r0) * Eq + cc;
    const short* gB1 = Wb + (size_t)(n0 + r1) * Eq + cc;
    short* la0 = lds_a + r0 * 40 + cc;
    short* la1 = lds_a + r1 * 40 + cc;
    short* lb0 = lds_b + r0 * 40 + cc;
    short* lb1 = lds_b + r1 * 40 + cc;

    f32x4 acc[4][4] = {};
    bf16x8 pa0 = *(const bf16x8*)gA0;
    bf16x8 pa1 = *(const bf16x8*)gA1;
    bf16x8 pb0 = *(const bf16x8*)gB0;
    bf16x8 pb1 = *(const bf16x8*)gB1;

#pragma unroll 1
    for (int e0 = 0; e0 < Eq; e0 += 32) {
        __syncthreads();
        *(bf16x8*)la0 = pa0; *(bf16x8*)la1 = pa1;
        *(bf16x8*)lb0 = pb0; *(bf16x8*)lb1 = pb1;
        if (e0 + 32 < Eq) {
            pa0 = *(const bf16x8*)(gA0 + e0 + 32);
            pa1 = *(const bf16x8*)(gA1 + e0 + 32);
            pb0 = *(const bf16x8*)(gB0 + e0 + 32);
            pb1 = *(const bf16x8*)(gB1 + e0 + 32);
        }
        __syncthreads();

        bf16x8 af[4], bfr[4];
#pragma unroll
        for (int i = 0; i < 4; ++i)
            af[i] = *(const bf16x8*)(lds_a + (wm * 64 + i * 16 + l15) * 40 + quad * 8);
#pragma unroll
        for (int j = 0; j < 4; ++j)
            bfr[j] = *(const bf16x8*)(lds_b + (wn * 64 + j * 16 + l15) * 40 + quad * 8);
#pragma unroll
        for (int i = 0; i < 4; ++i)
#pragma unroll
            for (int j = 0; j < 4; ++j)
                acc[i][j] = __builtin_amdgcn_mfma_f32_16x16x32_bf16(af[i], bfr[j], acc[i][j], 0, 0, 0);
    }

    const int mw = m0 + wm * 64;
    const int nw = n0 + wn * 64;
    const int h = nw >> 6;
#pragma unroll
    for (int i = 0; i < 4; ++i) {
        float ss[4] = {0.f, 0.f, 0.f, 0.f};
#pragma unroll
        for (int r = 0; r < 4; ++r) {
            int tok = mw + i * 16 + quad * 4 + r;
            int b = tok >> 11, l = tok & 2047;
#pragma unroll
            for (int j = 0; j < 4; ++j) {
                int d = (nw + j * 16 + l15) & 63;
                short sb = f2bf(acc[i][j][r]);
                float sv = bf2f(sb);
                ss[r] += sv * sv;
                size_t idx = transposed
                                 ? (((size_t)(b * Hq + h) * Dq + d) * Lq + l)
                                 : (((size_t)(b * Hq + h) * Lq + l) * Dq + d);
                outb[idx] = sb;
            }
        }
        if (x2 != nullptr) {
#pragma unroll
            for (int r = 0; r < 4; ++r) {
#pragma unroll
                for (int off = 1; off < 16; off <<= 1) ss[r] += __shfl_xor(ss[r], off);
            }
            if (l15 == 0) {
#pragma unroll
                for (int r = 0; r < 4; ++r) {
                    int tok = mw + i * 16 + quad * 4 + r;
                    int b = tok >> 11, l = tok & 2047;
                    x2[(size_t)(b * Hq + h) * Lq + l] = ss[r];
                }
            }
        }
    }
}

// Flash attention, scores = -||q-k||, fixed softmax max = 0.
// S^T = K.Q^T (swapped operands): lane holds P[q=l15][keys quad*4..+3] -> P is
// written to LDS as ONE packed b64 per ktile (uniform 4/bank = b64 floor) and
// read back as the K=32 A-fragment (b128, uniform 8/bank). PV stays at 8
// mfma_f32_16x16x32_bf16 per 64-key chunk. K/V staged with register prefetch.
// Grid (32, B*H) = 1024 blocks, 256 threads.
__global__ __launch_bounds__(256) void flash_kernel(const short* __restrict__ qb,
                                                    const short* __restrict__ kb,
                                                    const short* __restrict__ vT,
                                                    const float* __restrict__ q2,
                                                    const float* __restrict__ k2,
                                                    float* __restrict__ osum) {
    const int wave = threadIdx.x >> 6;
    const int lane = threadIdx.x & 63;
    const int l15 = lane & 15, quad = lane >> 4;
    const int bh = blockIdx.y;
    const int q0 = blockIdx.x * 64 + wave * 16;
    const short* qbh = qb + (size_t)bh * Lq * Dq;
    const short* kbh = kb + (size_t)bh * Lq * Dq;
    const short* vbh = vT + (size_t)bh * Dq * Lq;
    const float* q2h = q2 + (size_t)bh * Lq;
    const float* k2h = k2 + (size_t)bh * Lq;

    __shared__ __align__(16) short lds_k[64 * 72];
    __shared__ __align__(16) short lds_v[64 * 72];
    __shared__ __align__(16) short plds[4][16 * 72];  // P: rows=q(16), cols=keys(64)
    short* pl = plds[wave];

    // Q fragment (B-operand of S^T): lane l15 = q-row, cols quad*8..+7
    const short* qp = qbh + (size_t)(q0 + l15) * Dq + quad * 8;
    bf16x8 qf0 = *(const bf16x8*)qp;
    bf16x8 qf1 = *(const bf16x8*)(qp + 32);
    const float q2l = q2h[q0 + l15];

    // staging geometry: thread t covers 16B chunks t and t+256 of each 8KB tile
    const int row0 = threadIdx.x >> 3;
    const int row1 = 32 + row0;
    const int sc = (threadIdx.x & 7) * 8;
    short* lk0 = lds_k + row0 * 72 + sc;
    short* lk1 = lds_k + row1 * 72 + sc;
    short* lv0 = lds_v + row0 * 72 + sc;
    short* lv1 = lds_v + row1 * 72 + sc;

    f32x4 o[4] = {};
    float lsum = 0.f;

    // prologue: prefetch tile 0
    bf16x8 kp0 = *(const bf16x8*)(kbh + (size_t)row0 * Dq + sc);
    bf16x8 kp1 = *(const bf16x8*)(kbh + (size_t)row1 * Dq + sc);
    bf16x8 vp0 = *(const bf16x8*)(vbh + (size_t)row0 * Lq + sc);
    bf16x8 vp1 = *(const bf16x8*)(vbh + (size_t)row1 * Lq + sc);

#pragma unroll 1
    for (int k0 = 0; k0 < Lq; k0 += 64) {
        __syncthreads();
        *(bf16x8*)lk0 = kp0; *(bf16x8*)lk1 = kp1;
        *(bf16x8*)lv0 = vp0; *(bf16x8*)lv1 = vp1;
        if (k0 + 64 < Lq) {
            const short* ks = kbh + (size_t)(k0 + 64) * Dq;
            kp0 = *(const bf16x8*)(ks + (size_t)row0 * Dq + sc);
            kp1 = *(const bf16x8*)(ks + (size_t)row1 * Dq + sc);
            vp0 = *(const bf16x8*)(vbh + (size_t)row0 * Lq + k0 + 64 + sc);
            vp1 = *(const bf16x8*)(vbh + (size_t)row1 * Lq + k0 + 64 + sc);
        }
        __syncthreads();

        // scores: S^T = K.Q^T; lane -> P[q=l15][key=kt*16+quad*4+r]
#pragma unroll
        for (int kt = 0; kt < 4; ++kt) {
            bf16x8 kf0 = *(const bf16x8*)(lds_k + (kt * 16 + l15) * 72 + quad * 8);
            bf16x8 kf1 = *(const bf16x8*)(lds_k + (kt * 16 + l15) * 72 + 32 + quad * 8);
            f32x4 st = {0.f, 0.f, 0.f, 0.f};
            st = __builtin_amdgcn_mfma_f32_16x16x32_bf16(kf0, qf0, st, 0, 0, 0);
            st = __builtin_amdgcn_mfma_f32_16x16x32_bf16(kf1, qf1, st, 0, 0, 0);
            float4 k2v = *(const float4*)(k2h + k0 + kt * 16 + quad * 4);
            bf16x4 pw;
#pragma unroll
            for (int r = 0; r < 4; ++r) {
                float d2 = fmaxf(fmaf(st[r], -2.f, q2l + ((const float*)&k2v)[r]), 0.f);
                float pv = __expf(-__builtin_amdgcn_sqrtf(d2));
                lsum += pv;
                pw[r] = f2bf_fast(pv);
            }
            // packed b64 write: row q=l15, cols kt*16+quad*4..+3 (uniform 4/bank)
            *(bf16x4*)(pl + l15 * 72 + kt * 16 + quad * 4) = pw;
        }
        // PV: P back as K=32 A-fragment (b128), V as B-fragment (b128)
#pragma unroll
        for (int kc2 = 0; kc2 < 2; ++kc2) {
            bf16x8 pa = *(const bf16x8*)(pl + l15 * 72 + kc2 * 32 + quad * 8);
#pragma unroll
            for (int f = 0; f < 4; ++f) {
                bf16x8 vf = *(const bf16x8*)(lds_v + (f * 16 + l15) * 72 + kc2 * 32 + quad * 8);
                o[f] = __builtin_amdgcn_mfma_f32_16x16x32_bf16(pa, vf, o[f], 0, 0, 0);
            }
        }
    }

    // lsum: lane holds partial for q-row l15 (its quad's keys); reduce over quads
    lsum += __shfl_xor(lsum, 16);
    lsum += __shfl_xor(lsum, 32);
    // O lane layout: row=quad*4+r = q-row, col=l15 = d-within-16
    float lq[4];
#pragma unroll
    for (int r = 0; r < 4; ++r) lq[r] = __shfl(lsum, quad * 4 + r);
#pragma unroll
    for (int f = 0; f < 4; ++f) {
        float cs = o[f][0] / lq[0] + o[f][1] / lq[1] +
                   o[f][2] / lq[2] + o[f][3] / lq[3];
        cs += __shfl_xor(cs, 16);
        cs += __shfl_xor(cs, 32);
        if (quad == 0) atomicAdd(&osum[(size_t)bh * Dq + f * 16 + l15], cs);
    }
}

// out[b,j] = sum_e osum[b,e] * Wo[j,e]; one wave per output element
__global__ __launch_bounds__(256) void outproj_kernel(const float* __restrict__ osum,
                                                      const float* __restrict__ Wo,
                                                      float* __restrict__ out) {
    int idx = blockIdx.x * 4 + (threadIdx.x >> 6);
    int lane = threadIdx.x & 63;
    int b = idx >> 10, j = idx & 1023;
    const float* o = osum + (size_t)b * Eq;
    const float* w = Wo + (size_t)j * Eq;
    float4 s4 = {0.f, 0.f, 0.f, 0.f};
    for (int e = lane * 4; e < Eq; e += 256) {
        float4 ov = *(const float4*)(o + e);
        float4 wv = *(const float4*)(w + e);
        s4.x += ov.x * wv.x; s4.y += ov.y * wv.y;
        s4.z += ov.z * wv.z; s4.w += ov.w * wv.w;
    }
    float s = s4.x + s4.y + s4.z + s4.w;
#pragma unroll
    for (int off = 1; off < 64; off <<= 1) s += __shfl_xor(s, off);
    if (lane == 0) out[idx] = s;
}

extern "C" void kernel_launch(void* const* d_in, const int* in_sizes, int n_in,
                              void* d_out, int out_size, void* d_ws, size_t ws_size,
                              hipStream_t stream) {
    const float* Q  = (const float*)d_in[0];
    const float* K  = (const float*)d_in[1];
    const float* V  = (const float*)d_in[2];
    const float* Wq = (const float*)d_in[3];
    const float* Wk = (const float*)d_in[4];
    const float* Wv = (const float*)d_in[5];
    const float* Wo = (const float*)d_in[6];
    float* out = (float*)d_out;

    char* ws = (char*)d_ws;
    // [0,8M) qb | [8M,16M) kb | [16M,24M) vT | q2 | k2 | osum | [25M,55M) castb
    short* qb = (short*)ws;
    short* kb = (short*)(ws + (size_t)(8 << 20));
    short* vT = (short*)(ws + (size_t)(16 << 20));
    float* q2 = (float*)(ws + (size_t)(24 << 20));
    float* k2 = (float*)(ws + (size_t)(24 << 20) + (256 << 10));
    float* os = (float*)(ws + (size_t)(24 << 20) + (512 << 10));
    short* castb = (short*)(ws + (size_t)(25 << 20));

    cast_all<<<15362, 256, 0, stream>>>(Q, K, V, Wq, Wk, Wv, castb, os);
    proj3_kernel<<<dim3(32, 24), 256, 0, stream>>>(castb, qb, kb, vT, q2, k2);
    flash_kernel<<<dim3(32, 32), 256, 0, stream>>>(qb, kb, vT, q2, k2, os);
    outproj_kernel<<<512, 256, 0, stream>>>(os, Wo, out);
}